// Round 16
// baseline (172.895 us; speedup 1.0000x reference)
//
#include <hip/hip_runtime.h>

// L=1024, B=4, IN=D=256, H=8, HD=32, IN2D=16
// ws (2B units): q_bf[1M] k_bf[1M] v_t[1M] | e16[32M halves, layout [b][w][i][j][2]]
// then (floats): o_part[JS*1M] lsum_part[JS*32K]

typedef __attribute__((ext_vector_type(8))) short short8;
typedef __attribute__((ext_vector_type(4))) float f32x4;
typedef __attribute__((ext_vector_type(2))) _Float16 half2_t;
typedef unsigned short ushort_t;

#define JS_FIXED 4

__device__ inline unsigned short f2bf(float f) {
  unsigned int u = __float_as_uint(f);
  return (unsigned short)((u + 0x7FFFu + ((u >> 16) & 1u)) >> 16);
}

// bias MLP standalone: 8192 blocks, 2 points/thread, coalesced LDS-staged p reads,
// W2d in VGPRs (fp16 pairs), v_dot2_f32_f16 inner product.
__global__ __launch_bounds__(256) void bias_mlp(
    const float* __restrict__ p, const float* __restrict__ W2d,
    const float* __restrict__ b2d, unsigned int* __restrict__ e16)
{
  __shared__ unsigned int w2h[64];
  __shared__ float b2d_s[8];
  __shared__ __align__(16) float4 stage[4][64 * 5];  // per-wave staging, 5-float4 point stride
  const int t = threadIdx.x;

  if (t < 64) {
    half2_t hv;
    hv[0] = (_Float16)W2d[2 * t];
    hv[1] = (_Float16)W2d[2 * t + 1];
    w2h[t] = __builtin_bit_cast(unsigned int, hv);
  }
  if (t < 8) b2d_s[t] = b2d[t];
  __syncthreads();

  const int wv = t >> 6, lane = t & 63;
  const size_t blkbase = ((size_t)blockIdx.x << 9);   // 512 points per block
  const size_t pt0 = blkbase + ((size_t)wv << 7);
  const size_t pt1 = pt0 + 64;

  // issue ALL global loads up-front, fully coalesced (lane-contiguous float4s)
  const float4* p4 = (const float4*)p;
  float4 v0[4], v1[4];
#pragma unroll
  for (int c = 0; c < 4; ++c) v0[c] = p4[(pt0 << 2) + (c << 6) + lane];
#pragma unroll
  for (int c = 0; c < 4; ++c) v1[c] = p4[(pt1 << 2) + (c << 6) + lane];

  // W2d fp16 pairs -> 64 VGPRs (broadcast LDS reads, once per thread)
  unsigned int w2r[64];
#pragma unroll
  for (int i = 0; i < 16; ++i) {
    const uint4 q = *(const uint4*)&w2h[i * 4];
    w2r[4 * i + 0] = q.x; w2r[4 * i + 1] = q.y;
    w2r[4 * i + 2] = q.z; w2r[4 * i + 3] = q.w;
  }
  float b2r[8];
#pragma unroll
  for (int h = 0; h < 8; ++h) b2r[h] = b2d_s[h];

#pragma unroll
  for (int rnd = 0; rnd < 2; ++rnd) {
    // stage this round's chunk: float4 fi=(c*64+lane) belongs to point fi>>2, comp fi&3
#pragma unroll
    for (int c = 0; c < 4; ++c) {
      const int fi = (c << 6) + lane;
      stage[wv][(fi >> 2) * 5 + (fi & 3)] = rnd ? v1[c] : v0[c];
    }
    // each lane reads its own point's 64B (conflict-free: 80B stride)
    float4 P[4];
#pragma unroll
    for (int cc = 0; cc < 4; ++cc) P[cc] = stage[wv][lane * 5 + cc];

    const size_t n = (rnd ? pt1 : pt0) + lane;
    unsigned int ph[8];
#pragma unroll
    for (int c = 0; c < 4; ++c) {
      unsigned int lo, hi;
      asm("v_cvt_pkrtz_f16_f32 %0, %1, %2" : "=v"(lo) : "v"(P[c].x), "v"(P[c].y));
      asm("v_cvt_pkrtz_f16_f32 %0, %1, %2" : "=v"(hi) : "v"(P[c].z), "v"(P[c].w));
      ph[2 * c] = lo; ph[2 * c + 1] = hi;
    }
    float acc[8];
#pragma unroll
    for (int h = 0; h < 8; ++h) {
      float a = b2r[h];
#pragma unroll
      for (int k = 0; k < 8; ++k)
        asm("v_dot2_f32_f16 %0, %1, %2, %0" : "+v"(a) : "v"(ph[k]), "v"(w2r[h * 8 + k]));
      acc[h] = a;
    }
    const int b = (int)(n >> 20);
    const unsigned int ij = (unsigned int)(n & 0xFFFFFu);
#pragma unroll
    for (int w = 0; w < 4; ++w) {
      half2_t hv;
      hv[0] = (_Float16)acc[2 * w];
      hv[1] = (_Float16)acc[2 * w + 1];
      e16[(((size_t)((b << 2) + w)) << 20) + ij] = __builtin_bit_cast(unsigned int, hv);
    }
  }
}

__global__ __launch_bounds__(256) void qkv_proj(
    const float* __restrict__ s, const float* __restrict__ Wq,
    const float* __restrict__ Wk, const float* __restrict__ Wv,
    ushort_t* __restrict__ q_bf, ushort_t* __restrict__ k_bf, ushort_t* __restrict__ v_t)
{
  __shared__ float s_lds[8][256];
  const int t = threadIdx.x;
  const int b = blockIdx.x >> 7;          // fixed batch per block
  const int l0 = (blockIdx.x & 127) << 3; // 8 consecutive l
  for (int rr = 0; rr < 8; ++rr)
    s_lds[rr][t] = s[((size_t)(((l0 + rr) << 2) + b) << 8) + t];
  __syncthreads();
  float aq[8], ak[8], av[8];
#pragma unroll
  for (int rr = 0; rr < 8; ++rr) { aq[rr] = 0.f; ak[rr] = 0.f; av[rr] = 0.f; }
  for (int k = 0; k < 256; ++k) {
    const float wq = Wq[k * 256 + t];
    const float wk = Wk[k * 256 + t];
    const float wv = Wv[k * 256 + t];
#pragma unroll
    for (int rr = 0; rr < 8; ++rr) {
      const float sv = s_lds[rr][k];
      aq[rr] = fmaf(sv, wq, aq[rr]);
      ak[rr] = fmaf(sv, wk, ak[rr]);
      av[rr] = fmaf(sv, wv, av[rr]);
    }
  }
  const int h = t >> 5, dl = t & 31;
#pragma unroll
  for (int rr = 0; rr < 8; ++rr) {
    const int l = l0 + rr;
    q_bf[(((size_t)(b << 10) + l) << 8) + t] = f2bf(aq[rr] * 0.0625f);
    k_bf[((((size_t)((b << 3) + h) << 10) + l) << 5) + dl] = f2bf(ak[rr]);
  }
  short8 vv;
#pragma unroll
  for (int rr = 0; rr < 8; ++rr) vv[rr] = (short)f2bf(av[rr]);
  *(short8*)&v_t[((((size_t)((b << 3) + h) << 5) + dl) << 10) + l0] = vv;
}

template <int JS>
__global__ __launch_bounds__(256, 4) void attn_mfma(
    const ushort_t* __restrict__ q_bf, const ushort_t* __restrict__ k_bf,
    const ushort_t* __restrict__ v_t, const unsigned int* __restrict__ ep,
    float* __restrict__ o_part, float* __restrict__ lsum_part)
{
  __shared__ __align__(16) ushort_t p_lds[2][8][16][40];  // parity double-buffered

  const int t = threadIdx.x;
  // ---- bijective XCD swizzle ----
  const int flat = blockIdx.x + (blockIdx.y << 6) + (blockIdx.z << 8);  // 0..1023
  const int swz = ((flat & 7) << 7) + (flat >> 3);
  const int i0 = (swz & 63) << 4;
  const int b  = (swz >> 6) & 3;
  const int js = swz >> 8;

  const int w = t >> 6;      // wave -> heads 2w, 2w+1
  const int l = t & 63;
  const int lrow = l & 15;
  const int lgrp = l >> 4;

  short8 qa[2];
#pragma unroll
  for (int h2 = 0; h2 < 2; ++h2) {
    const int h = (w << 1) + h2;
    qa[h2] = *(const short8*)&q_bf[(((size_t)(b << 10) + i0 + lrow) << 8) + (h << 5) + (lgrp << 3)];
  }

  f32x4 o_acc[2][2];
  float ls[2][4];
#pragma unroll
  for (int h2 = 0; h2 < 2; ++h2) {
#pragma unroll
    for (int nh = 0; nh < 2; ++nh) o_acc[h2][nh] = (f32x4){0.f, 0.f, 0.f, 0.f};
#pragma unroll
    for (int r = 0; r < 4; ++r) ls[h2][r] = 0.f;
  }

  // e16 plane [b][w]: fully-coalesced reads (lane stride 4B)
  const size_t A0 = (((size_t)((b << 2) + w)) << 20) + ((size_t)(i0 + (lgrp << 2)) << 10) + lrow;

  auto LOADE = [&](int j0, unsigned int (&ub)[2][4]) {
#pragma unroll
    for (int jh = 0; jh < 2; ++jh)
#pragma unroll
      for (int r = 0; r < 4; ++r)
        ub[jh][r] = ep[A0 + ((size_t)r << 10) + (jh << 4) + j0];
  };

  auto COMPUTE = [&](int j0, unsigned int (&ub)[2][4], int pb) {
    // ---- Scores: D = Q*K^T + bias(C), exp in-register, P -> bf16 LDS ----
#pragma unroll
    for (int jh = 0; jh < 2; ++jh) {
#pragma unroll
      for (int h2 = 0; h2 < 2; ++h2) {
        const int h = (w << 1) + h2;
        const short8 kb = *(const short8*)&k_bf[((((size_t)((b << 3) + h) << 10) + j0 + (jh << 4) + lrow) << 5) + (lgrp << 3)];
        f32x4 cc;
#pragma unroll
        for (int r = 0; r < 4; ++r) {
          const half2_t hv = __builtin_bit_cast(half2_t, ub[jh][r]);
          cc[r] = (float)hv[h2];
        }
        f32x4 d = __builtin_amdgcn_mfma_f32_16x16x32_bf16(qa[h2], kb, cc, 0, 0, 0);
#pragma unroll
        for (int r = 0; r < 4; ++r) {
          const float ex = __expf(d[r]);
          ls[h2][r] += ex;
          p_lds[pb][h][(lgrp << 2) + r][(jh << 4) + lrow] = f2bf(ex);
        }
      }
    }
    // ---- PV: o += P * V; P from wave-local LDS (A-frag), V JIT from L2 (B-frag) ----
#pragma unroll
    for (int h2 = 0; h2 < 2; ++h2) {
      const int h = (w << 1) + h2;
      const short8 pa = *(const short8*)&p_lds[pb][h][lrow][lgrp << 3];
#pragma unroll
      for (int nh = 0; nh < 2; ++nh) {
        const short8 vb = *(const short8*)&v_t[((((size_t)((b << 3) + h) << 5) + (nh << 4) + lrow) << 10) + j0 + (lgrp << 3)];
        o_acc[h2][nh] = __builtin_amdgcn_mfma_f32_16x16x32_bf16(pa, vb, o_acc[h2][nh], 0, 0, 0);
      }
    }
  };

  constexpr int CHUNK = 1024 / JS;   // 256
  constexpr int NT = CHUNK / 32;     // 8 (even)
  const int jbeg = js * CHUNK;
  const int jlast = jbeg + CHUNK - 32;

  unsigned int ubA[2][4], ubB[2][4];
  LOADE(jbeg, ubA);
#pragma unroll 1
  for (int t2 = 0; t2 < NT; t2 += 2) {
    const int j0 = jbeg + (t2 << 5);
    const int jn1 = (j0 + 32 < jlast) ? (j0 + 32) : jlast;
    const int jn2 = (j0 + 64 < jlast) ? (j0 + 64) : jlast;
    LOADE(jn1, ubB);        // prefetch tile t2+1
    COMPUTE(j0, ubA, 0);
    LOADE(jn2, ubA);        // prefetch tile t2+2
    COMPUTE(j0 + 32, ubB, 1);
  }

  // ---- epilogue ----
#pragma unroll
  for (int h2 = 0; h2 < 2; ++h2) {
#pragma unroll
    for (int r = 0; r < 4; ++r) {
      float v = ls[h2][r];
      v += __shfl_xor(v, 1, 16);
      v += __shfl_xor(v, 2, 16);
      v += __shfl_xor(v, 4, 16);
      v += __shfl_xor(v, 8, 16);
      ls[h2][r] = v;
    }
  }
  const size_t obase = ((size_t)js << 20) + (((size_t)(b << 10) + i0) << 8);
#pragma unroll
  for (int h2 = 0; h2 < 2; ++h2) {
    const int h = (w << 1) + h2;
#pragma unroll
    for (int nh = 0; nh < 2; ++nh) {
      const int d = (h << 5) + (nh << 4) + lrow;
#pragma unroll
      for (int r = 0; r < 4; ++r)
        o_part[obase + ((size_t)((lgrp << 2) + r) << 8) + d] = o_acc[h2][nh][r];
    }
  }
  if (lrow == 0) {
#pragma unroll
    for (int h2 = 0; h2 < 2; ++h2) {
      const int h = (w << 1) + h2;
      float* lp = lsum_part + (((size_t)((js << 5) + (b << 3) + h)) << 10) + i0;
#pragma unroll
      for (int r = 0; r < 4; ++r)
        lp[(lgrp << 2) + r] = ls[h2][r];
    }
  }
}

__global__ __launch_bounds__(256) void out_proj(
    const float* __restrict__ o_part, const float* __restrict__ lsum_part,
    const float* __restrict__ Wo, const float* __restrict__ bo,
    float* __restrict__ out)
{
  constexpr int JS = JS_FIXED;
  __shared__ float o_lds[8][256];
  const int t = threadIdx.x;
  const int r0 = blockIdx.x << 3;
  const int h = t >> 5;
  for (int rr = 0; rr < 8; ++rr) {
    const int r = r0 + rr;
    const int l = r >> 2, bb = r & 3;
    const size_t base = (((size_t)(bb << 10) + l) << 8) + t;
    float acc = 0.f;
#pragma unroll
    for (int js = 0; js < JS; ++js)
      acc += o_part[((size_t)js << 20) + base];
    float lsv = 0.f;
#pragma unroll
    for (int js = 0; js < JS; ++js)
      lsv += lsum_part[(((size_t)((js << 5) + (bb << 3) + h)) << 10) + l];
    o_lds[rr][t] = acc / lsv;
  }
  __syncthreads();
  float accs[8];
#pragma unroll
  for (int rr = 0; rr < 8; ++rr) accs[rr] = 0.f;
  for (int k = 0; k < 256; ++k) {
    const float wo = Wo[k * 256 + t];
#pragma unroll
    for (int rr = 0; rr < 8; ++rr)
      accs[rr] = fmaf(o_lds[rr][k], wo, accs[rr]);
  }
  const float bov = bo[t];
#pragma unroll
  for (int rr = 0; rr < 8; ++rr)
    out[(size_t)(r0 + rr) * 256 + t] = accs[rr] + bov;
}

extern "C" void kernel_launch(void* const* d_in, const int* in_sizes, int n_in,
                              void* d_out, int out_size, void* d_ws, size_t ws_size,
                              hipStream_t stream)
{
  const float* s   = (const float*)d_in[0];
  const float* p   = (const float*)d_in[3];
  const float* Wq  = (const float*)d_in[4];
  const float* Wk  = (const float*)d_in[5];
  const float* Wv  = (const float*)d_in[6];
  const float* Wo  = (const float*)d_in[7];
  const float* bo  = (const float*)d_in[8];
  const float* W2d = (const float*)d_in[9];
  const float* b2d = (const float*)d_in[10];
  float* out = (float*)d_out;

  ushort_t* q_bf = (ushort_t*)d_ws;
  ushort_t* k_bf = q_bf + (1 << 20);
  ushort_t* v_t  = k_bf + (1 << 20);
  unsigned int* e16 = (unsigned int*)(v_t + (1 << 20));   // 16 planes * 1M uints = 64MiB
  float* o_part = (float*)((char*)e16 + ((size_t)1 << 26));
  float* lsum_part = o_part + ((size_t)JS_FIXED << 20);
  // total: 6MiB + 64MiB + 16MiB + 0.5MiB = 86.5MiB

  bias_mlp<<<dim3(8192), dim3(256), 0, stream>>>(p, W2d, b2d, e16);
  qkv_proj<<<dim3(512), dim3(256), 0, stream>>>(s, Wq, Wk, Wv, q_bf, k_bf, v_t);
  attn_mfma<JS_FIXED><<<dim3(64, 4, JS_FIXED), dim3(256), 0, stream>>>(
      q_bf, k_bf, v_t, e16, o_part, lsum_part);
  out_proj<<<dim3(512), dim3(256), 0, stream>>>(o_part, lsum_part, Wo, bo, out);
}

// Round 18
// 160.028 us; speedup vs baseline: 1.0804x; 1.0804x over previous
//
#include <hip/hip_runtime.h>

// L=1024, B=4, IN=D=256, H=8, HD=32, IN2D=16
// ws (2B units): q_bf[1M] k_bf[1M] v_t[1M] | e16[32M halves, layout [b][w][i][j][2]]
// then (floats): o_part[JS*1M] lsum_part[JS*32K]

typedef __attribute__((ext_vector_type(8))) short short8;
typedef __attribute__((ext_vector_type(4))) float f32x4;
typedef __attribute__((ext_vector_type(2))) _Float16 half2_t;
typedef unsigned short ushort_t;

#define JS_FIXED 4

__device__ inline unsigned short f2bf(float f) {
  unsigned int u = __float_as_uint(f);
  return (unsigned short)((u + 0x7FFFu + ((u >> 16) & 1u)) >> 16);
}

// prep: blocks 0..511 = QKV projection; blocks 512..1535 = bias MLP
// (long-lived: 16 points/thread, 2-deep pipelined nontemporal p loads).
__global__ __launch_bounds__(256) void prep(
    const float* __restrict__ s, const float* __restrict__ Wq,
    const float* __restrict__ Wk, const float* __restrict__ Wv,
    const float* __restrict__ p, const float* __restrict__ W2d,
    const float* __restrict__ b2d,
    ushort_t* __restrict__ q_bf, ushort_t* __restrict__ k_bf, ushort_t* __restrict__ v_t,
    unsigned int* __restrict__ e16)
{
  __shared__ float s_lds[8][256];
  __shared__ unsigned int w2h[64];   // W2d packed half2: w2h[h*8+k] = (W2d[h][2k], W2d[h][2k+1])
  __shared__ float b2d_s[8];
  const int t = threadIdx.x;

  if (blockIdx.x < 512) {
    // ---------------- QKV projection ----------------
    const int b = blockIdx.x >> 7;          // fixed batch per block
    const int l0 = (blockIdx.x & 127) << 3; // 8 consecutive l
    for (int rr = 0; rr < 8; ++rr)
      s_lds[rr][t] = s[((size_t)(((l0 + rr) << 2) + b) << 8) + t];
    __syncthreads();
    float aq[8], ak[8], av[8];
#pragma unroll
    for (int rr = 0; rr < 8; ++rr) { aq[rr] = 0.f; ak[rr] = 0.f; av[rr] = 0.f; }
    for (int k = 0; k < 256; ++k) {
      const float wq = Wq[k * 256 + t];
      const float wk = Wk[k * 256 + t];
      const float wv = Wv[k * 256 + t];
#pragma unroll
      for (int rr = 0; rr < 8; ++rr) {
        const float sv = s_lds[rr][k];
        aq[rr] = fmaf(sv, wq, aq[rr]);
        ak[rr] = fmaf(sv, wk, ak[rr]);
        av[rr] = fmaf(sv, wv, av[rr]);
      }
    }
    const int h = t >> 5, dl = t & 31;
#pragma unroll
    for (int rr = 0; rr < 8; ++rr) {
      const int l = l0 + rr;
      q_bf[(((size_t)(b << 10) + l) << 8) + t] = f2bf(aq[rr] * 0.0625f);
      k_bf[((((size_t)((b << 3) + h) << 10) + l) << 5) + dl] = f2bf(ak[rr]);
    }
    short8 vv;
#pragma unroll
    for (int rr = 0; rr < 8; ++rr) vv[rr] = (short)f2bf(av[rr]);
    *(short8*)&v_t[((((size_t)((b << 3) + h) << 5) + dl) << 10) + l0] = vv;
  } else {
    // ---------------- bias MLP: long-lived blocks, 16 pts/thread, 2-deep pipeline ----------------
    if (t < 64) {
      half2_t hv;
      hv[0] = (_Float16)W2d[2 * t];
      hv[1] = (_Float16)W2d[2 * t + 1];
      w2h[t] = __builtin_bit_cast(unsigned int, hv);
    }
    if (t < 8) b2d_s[t] = b2d[t];
    __syncthreads();

    // W2d fp16 pairs -> 64 VGPRs (broadcast LDS reads, once per thread)
    unsigned int w2r[64];
#pragma unroll
    for (int i = 0; i < 16; ++i) {
      const uint4 q = *(const uint4*)&w2h[i * 4];
      w2r[4 * i + 0] = q.x; w2r[4 * i + 1] = q.y;
      w2r[4 * i + 2] = q.z; w2r[4 * i + 3] = q.w;
    }
    float b2r[8];
#pragma unroll
    for (int h = 0; h < 8; ++h) b2r[h] = b2d_s[h];

    const size_t base = ((size_t)(blockIdx.x - 512)) << 12;  // 4096 points per block
    const f32x4* p4 = (const f32x4*)p;

    f32x4 PA[4], PB[4];
    auto LOADP = [&](int c, f32x4 (&R)[4]) {
      const size_t n = base + ((size_t)c << 8) + t;
#pragma unroll
      for (int cc = 0; cc < 4; ++cc)
        R[cc] = __builtin_nontemporal_load(&p4[(n << 2) + cc]);  // read-once: skip L2/L3
    };
    auto DOPT = [&](int c, f32x4 (&R)[4]) {
      const size_t n = base + ((size_t)c << 8) + t;
      unsigned int ph[8];
#pragma unroll
      for (int cc = 0; cc < 4; ++cc) {
        unsigned int lo, hi;
        asm("v_cvt_pkrtz_f16_f32 %0, %1, %2" : "=v"(lo) : "v"(R[cc][0]), "v"(R[cc][1]));
        asm("v_cvt_pkrtz_f16_f32 %0, %1, %2" : "=v"(hi) : "v"(R[cc][2]), "v"(R[cc][3]));
        ph[2 * cc] = lo; ph[2 * cc + 1] = hi;
      }
      float acc[8];
#pragma unroll
      for (int h = 0; h < 8; ++h) {
        float a = b2r[h];
#pragma unroll
        for (int k = 0; k < 8; ++k)
          asm("v_dot2_f32_f16 %0, %1, %2, %0" : "+v"(a) : "v"(ph[k]), "v"(w2r[h * 8 + k]));
        acc[h] = a;
      }
      const int b = (int)(n >> 20);
      const unsigned int ij = (unsigned int)(n & 0xFFFFFu);
#pragma unroll
      for (int w = 0; w < 4; ++w) {
        half2_t hv;
        hv[0] = (_Float16)acc[2 * w];
        hv[1] = (_Float16)acc[2 * w + 1];
        e16[(((size_t)((b << 2) + w)) << 20) + ij] = __builtin_bit_cast(unsigned int, hv);
      }
    };

    LOADP(0, PA);
#pragma unroll 1
    for (int c = 0; c < 16; c += 2) {
      LOADP(c + 1, PB);          // prefetch next chunk (younger than PA's loads)
      DOPT(c, PA);
      if (c + 2 < 16) LOADP(c + 2, PA);
      DOPT(c + 1, PB);
    }
  }
}

template <int JS>
__global__ __launch_bounds__(256, 4) void attn_mfma(
    const ushort_t* __restrict__ q_bf, const ushort_t* __restrict__ k_bf,
    const ushort_t* __restrict__ v_t, const unsigned int* __restrict__ ep,
    float* __restrict__ o_part, float* __restrict__ lsum_part)
{
  __shared__ __align__(16) ushort_t p_lds[2][8][16][40];  // parity double-buffered

  const int t = threadIdx.x;
  // ---- bijective XCD swizzle ----
  const int flat = blockIdx.x + (blockIdx.y << 6) + (blockIdx.z << 8);  // 0..1023
  const int swz = ((flat & 7) << 7) + (flat >> 3);
  const int i0 = (swz & 63) << 4;
  const int b  = (swz >> 6) & 3;
  const int js = swz >> 8;

  const int w = t >> 6;      // wave -> heads 2w, 2w+1
  const int l = t & 63;
  const int lrow = l & 15;
  const int lgrp = l >> 4;

  short8 qa[2];
#pragma unroll
  for (int h2 = 0; h2 < 2; ++h2) {
    const int h = (w << 1) + h2;
    qa[h2] = *(const short8*)&q_bf[(((size_t)(b << 10) + i0 + lrow) << 8) + (h << 5) + (lgrp << 3)];
  }

  f32x4 o_acc[2][2];
  float ls[2][4];
#pragma unroll
  for (int h2 = 0; h2 < 2; ++h2) {
#pragma unroll
    for (int nh = 0; nh < 2; ++nh) o_acc[h2][nh] = (f32x4){0.f, 0.f, 0.f, 0.f};
#pragma unroll
    for (int r = 0; r < 4; ++r) ls[h2][r] = 0.f;
  }

  // e16 plane [b][w]: fully-coalesced reads (lane stride 4B)
  const size_t A0 = (((size_t)((b << 2) + w)) << 20) + ((size_t)(i0 + (lgrp << 2)) << 10) + lrow;

  auto LOADE = [&](int j0, unsigned int (&ub)[2][4]) {
#pragma unroll
    for (int jh = 0; jh < 2; ++jh)
#pragma unroll
      for (int r = 0; r < 4; ++r)
        ub[jh][r] = ep[A0 + ((size_t)r << 10) + (jh << 4) + j0];
  };

  auto COMPUTE = [&](int j0, unsigned int (&ub)[2][4], int pb) {
    // ---- Scores: D = Q*K^T + bias(C), exp in-register, P -> bf16 LDS ----
#pragma unroll
    for (int jh = 0; jh < 2; ++jh) {
#pragma unroll
      for (int h2 = 0; h2 < 2; ++h2) {
        const int h = (w << 1) + h2;
        const short8 kb = *(const short8*)&k_bf[((((size_t)((b << 3) + h) << 10) + j0 + (jh << 4) + lrow) << 5) + (lgrp << 3)];
        f32x4 cc;
#pragma unroll
        for (int r = 0; r < 4; ++r) {
          const half2_t hv = __builtin_bit_cast(half2_t, ub[jh][r]);
          cc[r] = (float)hv[h2];
        }
        f32x4 d = __builtin_amdgcn_mfma_f32_16x16x32_bf16(qa[h2], kb, cc, 0, 0, 0);
#pragma unroll
        for (int r = 0; r < 4; ++r) {
          const float ex = __expf(d[r]);
          ls[h2][r] += ex;
          p_lds[pb][h][(lgrp << 2) + r][(jh << 4) + lrow] = f2bf(ex);
        }
      }
    }
    // ---- PV: o += P * V; P from wave-local LDS (A-frag), V JIT from L2 (B-frag) ----
#pragma unroll
    for (int h2 = 0; h2 < 2; ++h2) {
      const int h = (w << 1) + h2;
      const short8 pa = *(const short8*)&p_lds[pb][h][lrow][lgrp << 3];
#pragma unroll
      for (int nh = 0; nh < 2; ++nh) {
        const short8 vb = *(const short8*)&v_t[((((size_t)((b << 3) + h) << 5) + (nh << 4) + lrow) << 10) + j0 + (lgrp << 3)];
        o_acc[h2][nh] = __builtin_amdgcn_mfma_f32_16x16x32_bf16(pa, vb, o_acc[h2][nh], 0, 0, 0);
      }
    }
  };

  constexpr int CHUNK = 1024 / JS;   // 256
  constexpr int NT = CHUNK / 32;     // 8 (even)
  const int jbeg = js * CHUNK;
  const int jlast = jbeg + CHUNK - 32;

  unsigned int ubA[2][4], ubB[2][4];
  LOADE(jbeg, ubA);
#pragma unroll 1
  for (int t2 = 0; t2 < NT; t2 += 2) {
    const int j0 = jbeg + (t2 << 5);
    const int jn1 = (j0 + 32 < jlast) ? (j0 + 32) : jlast;
    const int jn2 = (j0 + 64 < jlast) ? (j0 + 64) : jlast;
    LOADE(jn1, ubB);        // prefetch tile t2+1
    COMPUTE(j0, ubA, 0);
    LOADE(jn2, ubA);        // prefetch tile t2+2
    COMPUTE(j0 + 32, ubB, 1);
  }

  // ---- epilogue ----
#pragma unroll
  for (int h2 = 0; h2 < 2; ++h2) {
#pragma unroll
    for (int r = 0; r < 4; ++r) {
      float v = ls[h2][r];
      v += __shfl_xor(v, 1, 16);
      v += __shfl_xor(v, 2, 16);
      v += __shfl_xor(v, 4, 16);
      v += __shfl_xor(v, 8, 16);
      ls[h2][r] = v;
    }
  }
  const size_t obase = ((size_t)js << 20) + (((size_t)(b << 10) + i0) << 8);
#pragma unroll
  for (int h2 = 0; h2 < 2; ++h2) {
    const int h = (w << 1) + h2;
#pragma unroll
    for (int nh = 0; nh < 2; ++nh) {
      const int d = (h << 5) + (nh << 4) + lrow;
#pragma unroll
      for (int r = 0; r < 4; ++r)
        o_part[obase + ((size_t)((lgrp << 2) + r) << 8) + d] = o_acc[h2][nh][r];
    }
  }
  if (lrow == 0) {
#pragma unroll
    for (int h2 = 0; h2 < 2; ++h2) {
      const int h = (w << 1) + h2;
      float* lp = lsum_part + (((size_t)((js << 5) + (b << 3) + h)) << 10) + i0;
#pragma unroll
      for (int r = 0; r < 4; ++r)
        lp[(lgrp << 2) + r] = ls[h2][r];
    }
  }
}

__global__ __launch_bounds__(256) void out_proj(
    const float* __restrict__ o_part, const float* __restrict__ lsum_part,
    const float* __restrict__ Wo, const float* __restrict__ bo,
    float* __restrict__ out)
{
  constexpr int JS = JS_FIXED;
  __shared__ float o_lds[8][256];
  const int t = threadIdx.x;
  const int r0 = blockIdx.x << 3;
  const int h = t >> 5;
  for (int rr = 0; rr < 8; ++rr) {
    const int r = r0 + rr;
    const int l = r >> 2, bb = r & 3;
    const size_t base = (((size_t)(bb << 10) + l) << 8) + t;
    float acc = 0.f;
#pragma unroll
    for (int js = 0; js < JS; ++js)
      acc += o_part[((size_t)js << 20) + base];
    float lsv = 0.f;
#pragma unroll
    for (int js = 0; js < JS; ++js)
      lsv += lsum_part[(((size_t)((js << 5) + (bb << 3) + h)) << 10) + l];
    o_lds[rr][t] = acc / lsv;
  }
  __syncthreads();
  float accs[8];
#pragma unroll
  for (int rr = 0; rr < 8; ++rr) accs[rr] = 0.f;
  for (int k = 0; k < 256; ++k) {
    const float wo = Wo[k * 256 + t];
#pragma unroll
    for (int rr = 0; rr < 8; ++rr)
      accs[rr] = fmaf(o_lds[rr][k], wo, accs[rr]);
  }
  const float bov = bo[t];
#pragma unroll
  for (int rr = 0; rr < 8; ++rr)
    out[(size_t)(r0 + rr) * 256 + t] = accs[rr] + bov;
}

extern "C" void kernel_launch(void* const* d_in, const int* in_sizes, int n_in,
                              void* d_out, int out_size, void* d_ws, size_t ws_size,
                              hipStream_t stream)
{
  const float* s   = (const float*)d_in[0];
  const float* p   = (const float*)d_in[3];
  const float* Wq  = (const float*)d_in[4];
  const float* Wk  = (const float*)d_in[5];
  const float* Wv  = (const float*)d_in[6];
  const float* Wo  = (const float*)d_in[7];
  const float* bo  = (const float*)d_in[8];
  const float* W2d = (const float*)d_in[9];
  const float* b2d = (const float*)d_in[10];
  float* out = (float*)d_out;

  ushort_t* q_bf = (ushort_t*)d_ws;
  ushort_t* k_bf = q_bf + (1 << 20);
  ushort_t* v_t  = k_bf + (1 << 20);
  unsigned int* e16 = (unsigned int*)(v_t + (1 << 20));   // 16 planes * 1M uints = 64MiB
  float* o_part = (float*)((char*)e16 + ((size_t)1 << 26));
  float* lsum_part = o_part + ((size_t)JS_FIXED << 20);
  // total: 6MiB + 64MiB + 16MiB + 0.5MiB = 86.5MiB

  prep<<<dim3(512 + 1024), dim3(256), 0, stream>>>(s, Wq, Wk, Wv, p, W2d, b2d,
                                                   q_bf, k_bf, v_t, e16);
  attn_mfma<JS_FIXED><<<dim3(64, 4, JS_FIXED), dim3(256), 0, stream>>>(
      q_bf, k_bf, v_t, e16, o_part, lsum_part);
  out_proj<<<dim3(512), dim3(256), 0, stream>>>(o_part, lsum_part, Wo, bo, out);
}

// Round 20
// 158.538 us; speedup vs baseline: 1.0906x; 1.0094x over previous
//
#include <hip/hip_runtime.h>

// L=1024, B=4, IN=D=256, H=8, HD=32, IN2D=16
// ws (2B units): q_bf[1M] k_bf[1M] v_t[1M] | (floats) o_part[JS*1M] lsum_part[JS*32K]
// Bias MLP fused into attention: e16 intermediate ELIMINATED (-128 MB traffic).

typedef __attribute__((ext_vector_type(8))) short short8;
typedef __attribute__((ext_vector_type(4))) short short4v;
typedef __attribute__((ext_vector_type(4))) float f32x4;
typedef unsigned short ushort_t;

#define JS_FIXED 4

__device__ inline unsigned short f2bf(float f) {
  unsigned int u = __float_as_uint(f);
  return (unsigned short)((u + 0x7FFFu + ((u >> 16) & 1u)) >> 16);
}

__global__ __launch_bounds__(256) void qkv_proj(
    const float* __restrict__ s, const float* __restrict__ Wq,
    const float* __restrict__ Wk, const float* __restrict__ Wv,
    ushort_t* __restrict__ q_bf, ushort_t* __restrict__ k_bf, ushort_t* __restrict__ v_t)
{
  __shared__ float s_lds[4][256];
  const int t = threadIdx.x;
  const int b = blockIdx.x >> 8;          // fixed batch per block
  const int l0 = (blockIdx.x & 255) << 2; // 4 consecutive l
  for (int rr = 0; rr < 4; ++rr)
    s_lds[rr][t] = s[((size_t)(((l0 + rr) << 2) + b) << 8) + t];
  __syncthreads();
  float aq[4], ak[4], av[4];
#pragma unroll
  for (int rr = 0; rr < 4; ++rr) { aq[rr] = 0.f; ak[rr] = 0.f; av[rr] = 0.f; }
  for (int k = 0; k < 256; ++k) {
    const float wq = Wq[k * 256 + t];
    const float wk = Wk[k * 256 + t];
    const float wv = Wv[k * 256 + t];
#pragma unroll
    for (int rr = 0; rr < 4; ++rr) {
      const float sv = s_lds[rr][k];
      aq[rr] = fmaf(sv, wq, aq[rr]);
      ak[rr] = fmaf(sv, wk, ak[rr]);
      av[rr] = fmaf(sv, wv, av[rr]);
    }
  }
  const int h = t >> 5, dl = t & 31;
#pragma unroll
  for (int rr = 0; rr < 4; ++rr) {
    const int l = l0 + rr;
    q_bf[(((size_t)(b << 10) + l) << 8) + t] = f2bf(aq[rr] * 0.0625f);
    k_bf[((((size_t)((b << 3) + h) << 10) + l) << 5) + dl] = f2bf(ak[rr]);
  }
  short4v vv;
#pragma unroll
  for (int rr = 0; rr < 4; ++rr) vv[rr] = (short)f2bf(av[rr]);
  *(short4v*)&v_t[((((size_t)((b << 3) + h) << 5) + dl) << 10) + l0] = vv;
}

template <int JS>
__global__ __launch_bounds__(256, 2) void attn_bias(
    const ushort_t* __restrict__ q_bf, const ushort_t* __restrict__ k_bf,
    const ushort_t* __restrict__ v_t, const float* __restrict__ p,
    const float* __restrict__ W2d, const float* __restrict__ b2d,
    float* __restrict__ o_part, float* __restrict__ lsum_part)
{
  // per-wave p staging: 16 KB half-tile, layout [c][i][j] float4 planes, XOR(c<<5) swizzle
  __shared__ __align__(16) unsigned char psg[4][16384];
  __shared__ __align__(16) ushort_t p_lds[8][16][40];  // single buffer (wave-local, in-order)

  const int t = threadIdx.x;
  // ---- bijective XCD swizzle ----
  const int flat = blockIdx.x + (blockIdx.y << 6) + (blockIdx.z << 8);  // 0..1023
  const int swz = ((flat & 7) << 7) + (flat >> 3);
  const int i0 = (swz & 63) << 4;
  const int b  = (swz >> 6) & 3;
  const int js = swz >> 8;

  const int w = t >> 6;      // wave -> heads 2w, 2w+1
  const int l = t & 63;
  const int lrow = l & 15;
  const int lgrp = l >> 4;

  short8 qa[2];
#pragma unroll
  for (int h2 = 0; h2 < 2; ++h2) {
    const int h = (w << 1) + h2;
    qa[h2] = *(const short8*)&q_bf[(((size_t)(b << 10) + i0 + lrow) << 8) + (h << 5) + (lgrp << 3)];
  }

  // wave's 2 heads' MLP weights as fp16 pairs (RNE, matching r14 numerics)
  unsigned int w2s[2][8];
  float b2[2];
#pragma unroll
  for (int h2 = 0; h2 < 2; ++h2) {
    const int h = (w << 1) + h2;
    b2[h2] = b2d[h];
#pragma unroll
    for (int k = 0; k < 8; ++k) {
      const unsigned short x0 = __builtin_bit_cast(unsigned short, (_Float16)W2d[h * 16 + 2 * k]);
      const unsigned short x1 = __builtin_bit_cast(unsigned short, (_Float16)W2d[h * 16 + 2 * k + 1]);
      w2s[h2][k] = (unsigned int)x0 | ((unsigned int)x1 << 16);
    }
  }

  f32x4 o_acc[2][2];
  float ls[2][4];
#pragma unroll
  for (int h2 = 0; h2 < 2; ++h2) {
#pragma unroll
    for (int nh = 0; nh < 2; ++nh) o_acc[h2][nh] = (f32x4){0.f, 0.f, 0.f, 0.f};
#pragma unroll
    for (int r = 0; r < 4; ++r) ls[h2][r] = 0.f;
  }

  const f32x4* pg = (const f32x4*)p;
  const int wc = l & 3, wj = l >> 2;  // staging write lane roles

  auto P_ISSUE = [&](int j16, f32x4 (&G)[16]) {
#pragma unroll
    for (int m = 0; m < 16; ++m)
      G[m] = pg[(((size_t)(b << 10) + i0 + m) << 12) + ((size_t)j16 << 2) + l];
  };
  auto P_WRITE = [&](f32x4 (&G)[16]) {
#pragma unroll
    for (int m = 0; m < 16; ++m)
      *(f32x4*)&psg[w][(wc << 12) + ((((m << 4) + wj) << 4) ^ (wc << 5))] = G[m];
  };
  auto BIAS = [&](float (&cb)[2][4]) {
#pragma unroll
    for (int r = 0; r < 4; ++r) {
      const int il = (lgrp << 2) + r;
      unsigned int ph[8];
#pragma unroll
      for (int c = 0; c < 4; ++c) {
        const f32x4 R = *(const f32x4*)&psg[w][(c << 12) + ((((il << 4) + lrow) << 4) ^ (c << 5))];
        unsigned int lo, hi;
        asm("v_cvt_pkrtz_f16_f32 %0, %1, %2" : "=v"(lo) : "v"(R[0]), "v"(R[1]));
        asm("v_cvt_pkrtz_f16_f32 %0, %1, %2" : "=v"(hi) : "v"(R[2]), "v"(R[3]));
        ph[2 * c] = lo; ph[2 * c + 1] = hi;
      }
#pragma unroll
      for (int h2 = 0; h2 < 2; ++h2) {
        float a = b2[h2];
#pragma unroll
        for (int k = 0; k < 8; ++k)
          asm("v_dot2_f32_f16 %0, %1, %2, %0" : "+v"(a) : "v"(ph[k]), "v"(w2s[h2][k]));
        cb[h2][r] = a;
      }
    }
  };
  auto KLOAD = [&](int j0, int jh, short8 (&kb)[2]) {
#pragma unroll
    for (int h2 = 0; h2 < 2; ++h2) {
      const int h = (w << 1) + h2;
      kb[h2] = *(const short8*)&k_bf[((((size_t)((b << 3) + h) << 10) + j0 + (jh << 4) + lrow) << 5) + (lgrp << 3)];
    }
  };
  auto VLOAD = [&](int j0, short8 (&vb)[2][2]) {
#pragma unroll
    for (int h2 = 0; h2 < 2; ++h2) {
      const int h = (w << 1) + h2;
#pragma unroll
      for (int nh = 0; nh < 2; ++nh)
        vb[h2][nh] = *(const short8*)&v_t[((((size_t)((b << 3) + h) << 5) + (nh << 4) + lrow) << 10) + j0 + (lgrp << 3)];
    }
  };
  auto SCORES = [&](int jh, float (&cb)[2][4], short8 (&kb)[2]) {
#pragma unroll
    for (int h2 = 0; h2 < 2; ++h2) {
      const int h = (w << 1) + h2;
      f32x4 cc;
#pragma unroll
      for (int r = 0; r < 4; ++r) cc[r] = cb[h2][r];
      f32x4 d = __builtin_amdgcn_mfma_f32_16x16x32_bf16(qa[h2], kb[h2], cc, 0, 0, 0);
#pragma unroll
      for (int r = 0; r < 4; ++r) {
        const float ex = __expf(d[r]);
        ls[h2][r] += ex;
        p_lds[h][(lgrp << 2) + r][(jh << 4) + lrow] = f2bf(ex);
      }
    }
  };

  constexpr int CHUNK = 1024 / JS;   // 256
  constexpr int NT = CHUNK / 32;     // 8
  const int jbeg = js * CHUNK;

  f32x4 GA[16], GB[16];
  short8 kb0[2], kb1[2], vb[2][2];

  P_ISSUE(jbeg, GA);     // half0 of tile 0
  P_WRITE(GA);

#pragma unroll 1
  for (int t2 = 0; t2 < NT; ++t2) {
    const int j0 = jbeg + (t2 << 5);
    float c0[2][4], c1[2][4];

    KLOAD(j0, 0, kb0);          // older than GB -> MFMA wait won't drain p stream
    P_ISSUE(j0 + 16, GB);       // half1 of current tile
    BIAS(c0);                   // consume half0 (LDS)
    SCORES(0, c0, kb0);
    P_WRITE(GB);                // waits GB only; region now holds half1

    KLOAD(j0, 1, kb1);
    VLOAD(j0, vb);
    if (t2 + 1 < NT) P_ISSUE(j0 + 32, GA);   // half0 of next tile (youngest)
    BIAS(c1);                   // consume half1
    SCORES(1, c1, kb1);

    // PV over full 32-j tile
#pragma unroll
    for (int h2 = 0; h2 < 2; ++h2) {
      const int h = (w << 1) + h2;
      const short8 pa = *(const short8*)&p_lds[h][lrow][lgrp << 3];
#pragma unroll
      for (int nh = 0; nh < 2; ++nh)
        o_acc[h2][nh] = __builtin_amdgcn_mfma_f32_16x16x32_bf16(pa, vb[h2][nh], o_acc[h2][nh], 0, 0, 0);
    }
    if (t2 + 1 < NT) P_WRITE(GA);   // stage next tile's half0 (latency hidden under PV)
  }

  // ---- epilogue ----
#pragma unroll
  for (int h2 = 0; h2 < 2; ++h2) {
#pragma unroll
    for (int r = 0; r < 4; ++r) {
      float v = ls[h2][r];
      v += __shfl_xor(v, 1, 16);
      v += __shfl_xor(v, 2, 16);
      v += __shfl_xor(v, 4, 16);
      v += __shfl_xor(v, 8, 16);
      ls[h2][r] = v;
    }
  }
  const size_t obase = ((size_t)js << 20) + (((size_t)(b << 10) + i0) << 8);
#pragma unroll
  for (int h2 = 0; h2 < 2; ++h2) {
    const int h = (w << 1) + h2;
#pragma unroll
    for (int nh = 0; nh < 2; ++nh) {
      const int d = (h << 5) + (nh << 4) + lrow;
#pragma unroll
      for (int r = 0; r < 4; ++r)
        o_part[obase + ((size_t)((lgrp << 2) + r) << 8) + d] = o_acc[h2][nh][r];
    }
  }
  if (lrow == 0) {
#pragma unroll
    for (int h2 = 0; h2 < 2; ++h2) {
      const int h = (w << 1) + h2;
      float* lp = lsum_part + (((size_t)((js << 5) + (b << 3) + h)) << 10) + i0;
#pragma unroll
      for (int r = 0; r < 4; ++r)
        lp[(lgrp << 2) + r] = ls[h2][r];
    }
  }
}

__global__ __launch_bounds__(256) void out_proj(
    const float* __restrict__ o_part, const float* __restrict__ lsum_part,
    const float* __restrict__ Wo, const float* __restrict__ bo,
    float* __restrict__ out)
{
  constexpr int JS = JS_FIXED;
  __shared__ float o_lds[8][256];
  const int t = threadIdx.x;
  const int r0 = blockIdx.x << 3;
  const int h = t >> 5;
  for (int rr = 0; rr < 8; ++rr) {
    const int r = r0 + rr;
    const int l = r >> 2, bb = r & 3;
    const size_t base = (((size_t)(bb << 10) + l) << 8) + t;
    float acc = 0.f;
#pragma unroll
    for (int js = 0; js < JS; ++js)
      acc += o_part[((size_t)js << 20) + base];
    float lsv = 0.f;
#pragma unroll
    for (int js = 0; js < JS; ++js)
      lsv += lsum_part[(((size_t)((js << 5) + (bb << 3) + h)) << 10) + l];
    o_lds[rr][t] = acc / lsv;
  }
  __syncthreads();
  float accs[8];
#pragma unroll
  for (int rr = 0; rr < 8; ++rr) accs[rr] = 0.f;
  for (int k = 0; k < 256; ++k) {
    const float wo = Wo[k * 256 + t];
#pragma unroll
    for (int rr = 0; rr < 8; ++rr)
      accs[rr] = fmaf(o_lds[rr][k], wo, accs[rr]);
  }
  const float bov = bo[t];
#pragma unroll
  for (int rr = 0; rr < 8; ++rr)
    out[(size_t)(r0 + rr) * 256 + t] = accs[rr] + bov;
}

extern "C" void kernel_launch(void* const* d_in, const int* in_sizes, int n_in,
                              void* d_out, int out_size, void* d_ws, size_t ws_size,
                              hipStream_t stream)
{
  const float* s   = (const float*)d_in[0];
  const float* p   = (const float*)d_in[3];
  const float* Wq  = (const float*)d_in[4];
  const float* Wk  = (const float*)d_in[5];
  const float* Wv  = (const float*)d_in[6];
  const float* Wo  = (const float*)d_in[7];
  const float* bo  = (const float*)d_in[8];
  const float* W2d = (const float*)d_in[9];
  const float* b2d = (const float*)d_in[10];
  float* out = (float*)d_out;

  ushort_t* q_bf = (ushort_t*)d_ws;
  ushort_t* k_bf = q_bf + (1 << 20);
  ushort_t* v_t  = k_bf + (1 << 20);
  float* o_part = (float*)(v_t + (1 << 20));
  float* lsum_part = o_part + ((size_t)JS_FIXED << 20);
  // total: 6MiB + 16MiB + 0.5MiB = 22.5MiB (e16 eliminated)

  qkv_proj<<<dim3(1024), dim3(256), 0, stream>>>(s, Wq, Wk, Wv, q_bf, k_bf, v_t);
  attn_bias<JS_FIXED><<<dim3(64, 4, JS_FIXED), dim3(256), 0, stream>>>(
      q_bf, k_bf, v_t, p, W2d, b2d, o_part, lsum_part);
  out_proj<<<dim3(512), dim3(256), 0, stream>>>(o_part, lsum_part, Wo, bo, out);
}

// Round 21
// 139.364 us; speedup vs baseline: 1.2406x; 1.1376x over previous
//
#include <hip/hip_runtime.h>

// L=1024, B=4, IN=D=256, H=8, HD=32, IN2D=16
// ws (2B units): q_bf[1M] k_bf[1M] v_t[1M] | e16[32M halves, layout [b][w][i][j][2]]
// then (floats): o_part[JS*1M] lsum_part[JS*32K]
// ROUND-14 MEASURED-BEST CONFIG (139.8 us): merged prep (qkv + bias-dot2) +
// pipelined attn_mfma + out_proj. Fusion/demerge/nt variants all regressed.

typedef __attribute__((ext_vector_type(8))) short short8;
typedef __attribute__((ext_vector_type(4))) float f32x4;
typedef __attribute__((ext_vector_type(2))) _Float16 half2_t;
typedef unsigned short ushort_t;

#define JS_FIXED 4

__device__ inline unsigned short f2bf(float f) {
  unsigned int u = __float_as_uint(f);
  return (unsigned short)((u + 0x7FFFu + ((u >> 16) & 1u)) >> 16);
}

// prep: blocks 0..511 = QKV projection; blocks 512..8703 = bias MLP (2 points/thread,
// W2d held as fp16 pairs in 64 VGPRs, v_dot2_f32_f16 inner product).
__global__ __launch_bounds__(256) void prep(
    const float* __restrict__ s, const float* __restrict__ Wq,
    const float* __restrict__ Wk, const float* __restrict__ Wv,
    const float* __restrict__ p, const float* __restrict__ W2d,
    const float* __restrict__ b2d,
    ushort_t* __restrict__ q_bf, ushort_t* __restrict__ k_bf, ushort_t* __restrict__ v_t,
    unsigned int* __restrict__ e16)
{
  __shared__ float s_lds[8][256];
  __shared__ unsigned int w2h[64];   // W2d as packed half2: w2h[h*8+k] = (W2d[h][2k], W2d[h][2k+1])
  __shared__ float b2d_s[8];
  const int t = threadIdx.x;

  if (blockIdx.x < 512) {
    // ---------------- QKV projection ----------------
    const int b = blockIdx.x >> 7;          // fixed batch per block
    const int l0 = (blockIdx.x & 127) << 3; // 8 consecutive l
    for (int rr = 0; rr < 8; ++rr)
      s_lds[rr][t] = s[((size_t)(((l0 + rr) << 2) + b) << 8) + t];
    __syncthreads();
    float aq[8], ak[8], av[8];
#pragma unroll
    for (int rr = 0; rr < 8; ++rr) { aq[rr] = 0.f; ak[rr] = 0.f; av[rr] = 0.f; }
    for (int k = 0; k < 256; ++k) {
      const float wq = Wq[k * 256 + t];
      const float wk = Wk[k * 256 + t];
      const float wv = Wv[k * 256 + t];
#pragma unroll
      for (int rr = 0; rr < 8; ++rr) {
        const float sv = s_lds[rr][k];
        aq[rr] = fmaf(sv, wq, aq[rr]);
        ak[rr] = fmaf(sv, wk, ak[rr]);
        av[rr] = fmaf(sv, wv, av[rr]);
      }
    }
    const int h = t >> 5, dl = t & 31;
#pragma unroll
    for (int rr = 0; rr < 8; ++rr) {
      const int l = l0 + rr;
      q_bf[(((size_t)(b << 10) + l) << 8) + t] = f2bf(aq[rr] * 0.0625f);
      k_bf[((((size_t)((b << 3) + h) << 10) + l) << 5) + dl] = f2bf(ak[rr]);
    }
    short8 vv;
#pragma unroll
    for (int rr = 0; rr < 8; ++rr) vv[rr] = (short)f2bf(av[rr]);
    *(short8*)&v_t[((((size_t)((b << 3) + h) << 5) + dl) << 10) + l0] = vv;
  } else {
    // ---------------- bias MLP: 2 points per thread ----------------
    if (t < 64) {
      half2_t hv;
      hv[0] = (_Float16)W2d[2 * t];
      hv[1] = (_Float16)W2d[2 * t + 1];
      w2h[t] = __builtin_bit_cast(unsigned int, hv);
    }
    if (t < 8) b2d_s[t] = b2d[t];
    __syncthreads();

    const size_t base = (((size_t)blockIdx.x - 512) << 9);  // 512 points per block
    const size_t n0 = base + t;
    const size_t n1 = n0 + 256;

    // issue both points' p loads up-front (8 dwordx4, contiguous aggregate)
    const float4* p4 = (const float4*)p;
    float4 P0[4], P1[4];
#pragma unroll
    for (int c = 0; c < 4; ++c) P0[c] = p4[(n0 << 2) + c];
#pragma unroll
    for (int c = 0; c < 4; ++c) P1[c] = p4[(n1 << 2) + c];

    // W2d fp16 pairs -> 64 VGPRs (broadcast LDS reads, once per thread)
    unsigned int w2r[64];
#pragma unroll
    for (int i = 0; i < 16; ++i) {
      const uint4 q = *(const uint4*)&w2h[i * 4];
      w2r[4 * i + 0] = q.x; w2r[4 * i + 1] = q.y;
      w2r[4 * i + 2] = q.z; w2r[4 * i + 3] = q.w;
    }
    float b2r[8];
#pragma unroll
    for (int h = 0; h < 8; ++h) b2r[h] = b2d_s[h];

#pragma unroll
    for (int pt = 0; pt < 2; ++pt) {
      const size_t n = pt ? n1 : n0;
      const float4* P = pt ? P1 : P0;
      // p -> packed fp16 (RTZ; verified absmax-neutral in round 14)
      unsigned int ph[8];
#pragma unroll
      for (int c = 0; c < 4; ++c) {
        unsigned int lo, hi;
        asm("v_cvt_pkrtz_f16_f32 %0, %1, %2" : "=v"(lo) : "v"(P[c].x), "v"(P[c].y));
        asm("v_cvt_pkrtz_f16_f32 %0, %1, %2" : "=v"(hi) : "v"(P[c].z), "v"(P[c].w));
        ph[2 * c] = lo; ph[2 * c + 1] = hi;
      }
      float acc[8];
#pragma unroll
      for (int h = 0; h < 8; ++h) {
        float a = b2r[h];
#pragma unroll
        for (int k = 0; k < 8; ++k)
          asm("v_dot2_f32_f16 %0, %1, %2, %0" : "+v"(a) : "v"(ph[k]), "v"(w2r[h * 8 + k]));
        acc[h] = a;
      }
      const int b = (int)(n >> 20);
      const unsigned int ij = (unsigned int)(n & 0xFFFFFu);
#pragma unroll
      for (int w = 0; w < 4; ++w) {
        half2_t hv;
        hv[0] = (_Float16)acc[2 * w];
        hv[1] = (_Float16)acc[2 * w + 1];
        e16[(((size_t)((b << 2) + w)) << 20) + ij] = __builtin_bit_cast(unsigned int, hv);
      }
    }
  }
}

template <int JS>
__global__ __launch_bounds__(256, 4) void attn_mfma(
    const ushort_t* __restrict__ q_bf, const ushort_t* __restrict__ k_bf,
    const ushort_t* __restrict__ v_t, const unsigned int* __restrict__ ep,
    float* __restrict__ o_part, float* __restrict__ lsum_part)
{
  __shared__ __align__(16) ushort_t p_lds[2][8][16][40];  // parity double-buffered

  const int t = threadIdx.x;
  // ---- bijective XCD swizzle ----
  const int flat = blockIdx.x + (blockIdx.y << 6) + (blockIdx.z << 8);  // 0..1023
  const int swz = ((flat & 7) << 7) + (flat >> 3);
  const int i0 = (swz & 63) << 4;
  const int b  = (swz >> 6) & 3;
  const int js = swz >> 8;

  const int w = t >> 6;      // wave -> heads 2w, 2w+1
  const int l = t & 63;
  const int lrow = l & 15;
  const int lgrp = l >> 4;

  short8 qa[2];
#pragma unroll
  for (int h2 = 0; h2 < 2; ++h2) {
    const int h = (w << 1) + h2;
    qa[h2] = *(const short8*)&q_bf[(((size_t)(b << 10) + i0 + lrow) << 8) + (h << 5) + (lgrp << 3)];
  }

  f32x4 o_acc[2][2];
  float ls[2][4];
#pragma unroll
  for (int h2 = 0; h2 < 2; ++h2) {
#pragma unroll
    for (int nh = 0; nh < 2; ++nh) o_acc[h2][nh] = (f32x4){0.f, 0.f, 0.f, 0.f};
#pragma unroll
    for (int r = 0; r < 4; ++r) ls[h2][r] = 0.f;
  }

  // e16 plane [b][w]: fully-coalesced reads (lane stride 4B)
  const size_t A0 = (((size_t)((b << 2) + w)) << 20) + ((size_t)(i0 + (lgrp << 2)) << 10) + lrow;

  auto LOADE = [&](int j0, unsigned int (&ub)[2][4]) {
#pragma unroll
    for (int jh = 0; jh < 2; ++jh)
#pragma unroll
      for (int r = 0; r < 4; ++r)
        ub[jh][r] = ep[A0 + ((size_t)r << 10) + (jh << 4) + j0];
  };

  auto COMPUTE = [&](int j0, unsigned int (&ub)[2][4], int pb) {
    // ---- Scores: D = Q*K^T + bias(C), exp in-register, P -> bf16 LDS ----
#pragma unroll
    for (int jh = 0; jh < 2; ++jh) {
#pragma unroll
      for (int h2 = 0; h2 < 2; ++h2) {
        const int h = (w << 1) + h2;
        const short8 kb = *(const short8*)&k_bf[((((size_t)((b << 3) + h) << 10) + j0 + (jh << 4) + lrow) << 5) + (lgrp << 3)];
        f32x4 cc;
#pragma unroll
        for (int r = 0; r < 4; ++r) {
          const half2_t hv = __builtin_bit_cast(half2_t, ub[jh][r]);
          cc[r] = (float)hv[h2];
        }
        f32x4 d = __builtin_amdgcn_mfma_f32_16x16x32_bf16(qa[h2], kb, cc, 0, 0, 0);
#pragma unroll
        for (int r = 0; r < 4; ++r) {
          const float ex = __expf(d[r]);
          ls[h2][r] += ex;
          p_lds[pb][h][(lgrp << 2) + r][(jh << 4) + lrow] = f2bf(ex);
        }
      }
    }
    // ---- PV: o += P * V; P from wave-local LDS (A-frag), V JIT from L2 (B-frag) ----
#pragma unroll
    for (int h2 = 0; h2 < 2; ++h2) {
      const int h = (w << 1) + h2;
      const short8 pa = *(const short8*)&p_lds[pb][h][lrow][lgrp << 3];
#pragma unroll
      for (int nh = 0; nh < 2; ++nh) {
        const short8 vb = *(const short8*)&v_t[((((size_t)((b << 3) + h) << 5) + (nh << 4) + lrow) << 10) + j0 + (lgrp << 3)];
        o_acc[h2][nh] = __builtin_amdgcn_mfma_f32_16x16x32_bf16(pa, vb, o_acc[h2][nh], 0, 0, 0);
      }
    }
  };

  constexpr int CHUNK = 1024 / JS;   // 256
  constexpr int NT = CHUNK / 32;     // 8 (even)
  const int jbeg = js * CHUNK;
  const int jlast = jbeg + CHUNK - 32;

  unsigned int ubA[2][4], ubB[2][4];
  LOADE(jbeg, ubA);
#pragma unroll 1
  for (int t2 = 0; t2 < NT; t2 += 2) {
    const int j0 = jbeg + (t2 << 5);
    const int jn1 = (j0 + 32 < jlast) ? (j0 + 32) : jlast;
    const int jn2 = (j0 + 64 < jlast) ? (j0 + 64) : jlast;
    LOADE(jn1, ubB);        // prefetch tile t2+1
    COMPUTE(j0, ubA, 0);
    LOADE(jn2, ubA);        // prefetch tile t2+2
    COMPUTE(j0 + 32, ubB, 1);
  }

  // ---- epilogue ----
#pragma unroll
  for (int h2 = 0; h2 < 2; ++h2) {
#pragma unroll
    for (int r = 0; r < 4; ++r) {
      float v = ls[h2][r];
      v += __shfl_xor(v, 1, 16);
      v += __shfl_xor(v, 2, 16);
      v += __shfl_xor(v, 4, 16);
      v += __shfl_xor(v, 8, 16);
      ls[h2][r] = v;
    }
  }
  const size_t obase = ((size_t)js << 20) + (((size_t)(b << 10) + i0) << 8);
#pragma unroll
  for (int h2 = 0; h2 < 2; ++h2) {
    const int h = (w << 1) + h2;
#pragma unroll
    for (int nh = 0; nh < 2; ++nh) {
      const int d = (h << 5) + (nh << 4) + lrow;
#pragma unroll
      for (int r = 0; r < 4; ++r)
        o_part[obase + ((size_t)((lgrp << 2) + r) << 8) + d] = o_acc[h2][nh][r];
    }
  }
  if (lrow == 0) {
#pragma unroll
    for (int h2 = 0; h2 < 2; ++h2) {
      const int h = (w << 1) + h2;
      float* lp = lsum_part + (((size_t)((js << 5) + (b << 3) + h)) << 10) + i0;
#pragma unroll
      for (int r = 0; r < 4; ++r)
        lp[(lgrp << 2) + r] = ls[h2][r];
    }
  }
}

__global__ __launch_bounds__(256) void out_proj(
    const float* __restrict__ o_part, const float* __restrict__ lsum_part,
    const float* __restrict__ Wo, const float* __restrict__ bo,
    float* __restrict__ out)
{
  constexpr int JS = JS_FIXED;
  __shared__ float o_lds[8][256];
  const int t = threadIdx.x;
  const int r0 = blockIdx.x << 3;
  const int h = t >> 5;
  for (int rr = 0; rr < 8; ++rr) {
    const int r = r0 + rr;
    const int l = r >> 2, bb = r & 3;
    const size_t base = (((size_t)(bb << 10) + l) << 8) + t;
    float acc = 0.f;
#pragma unroll
    for (int js = 0; js < JS; ++js)
      acc += o_part[((size_t)js << 20) + base];
    float lsv = 0.f;
#pragma unroll
    for (int js = 0; js < JS; ++js)
      lsv += lsum_part[(((size_t)((js << 5) + (bb << 3) + h)) << 10) + l];
    o_lds[rr][t] = acc / lsv;
  }
  __syncthreads();
  float accs[8];
#pragma unroll
  for (int rr = 0; rr < 8; ++rr) accs[rr] = 0.f;
  for (int k = 0; k < 256; ++k) {
    const float wo = Wo[k * 256 + t];
#pragma unroll
    for (int rr = 0; rr < 8; ++rr)
      accs[rr] = fmaf(o_lds[rr][k], wo, accs[rr]);
  }
  const float bov = bo[t];
#pragma unroll
  for (int rr = 0; rr < 8; ++rr)
    out[(size_t)(r0 + rr) * 256 + t] = accs[rr] + bov;
}

extern "C" void kernel_launch(void* const* d_in, const int* in_sizes, int n_in,
                              void* d_out, int out_size, void* d_ws, size_t ws_size,
                              hipStream_t stream)
{
  const float* s   = (const float*)d_in[0];
  const float* p   = (const float*)d_in[3];
  const float* Wq  = (const float*)d_in[4];
  const float* Wk  = (const float*)d_in[5];
  const float* Wv  = (const float*)d_in[6];
  const float* Wo  = (const float*)d_in[7];
  const float* bo  = (const float*)d_in[8];
  const float* W2d = (const float*)d_in[9];
  const float* b2d = (const float*)d_in[10];
  float* out = (float*)d_out;

  ushort_t* q_bf = (ushort_t*)d_ws;
  ushort_t* k_bf = q_bf + (1 << 20);
  ushort_t* v_t  = k_bf + (1 << 20);
  unsigned int* e16 = (unsigned int*)(v_t + (1 << 20));   // 16 planes * 1M uints = 64MiB
  float* o_part = (float*)((char*)e16 + ((size_t)1 << 26));
  float* lsum_part = o_part + ((size_t)JS_FIXED << 20);
  // total: 6MiB + 64MiB + 16MiB + 0.5MiB = 86.5MiB

  prep<<<dim3(512 + 8192), dim3(256), 0, stream>>>(s, Wq, Wk, Wv, p, W2d, b2d,
                                                   q_bf, k_bf, v_t, e16);
  attn_mfma<JS_FIXED><<<dim3(64, 4, JS_FIXED), dim3(256), 0, stream>>>(
      q_bf, k_bf, v_t, e16, o_part, lsum_part);
  out_proj<<<dim3(512), dim3(256), 0, stream>>>(o_part, lsum_part, Wo, bo, out);
}